// Round 1
// baseline (144.674 us; speedup 1.0000x reference)
//
#include <hip/hip_runtime.h>

static constexpr int N_ = 4;
static constexpr int C_ = 9;
static constexpr int D_ = 16;
static constexpr int HWp = 1024 * 1024;
static constexpr int CELLS = D_ * D_ * D_;  // 4096

// Fold the 1x1 conv's grid-channel part into the grid:
// pre[n][cell] = float4( sum_c w[0,c]*g, sum_c w[1,c]*g, sum_c w[2,c]*g, 0 )
__global__ __launch_bounds__(256) void fold_grid_kernel(
    const float* __restrict__ grid, const float* __restrict__ cw,
    float4* __restrict__ pre)
{
    int t = blockIdx.x * blockDim.x + threadIdx.x;
    if (t >= N_ * CELLS) return;
    int n = t >> 12;
    int cell = t & (CELLS - 1);
    const float* g = grid + ((size_t)n * C_) * CELLS + cell;
    float a0 = 0.f, a1 = 0.f, a2 = 0.f;
#pragma unroll
    for (int c = 0; c < C_; ++c) {
        float v = g[(size_t)c * CELLS];
        a0 = fmaf(cw[c], v, a0);
        a1 = fmaf(cw[12 + c], v, a1);
        a2 = fmaf(cw[24 + c], v, a2);
    }
    pre[t] = make_float4(a0, a1, a2, 0.f);
}

__device__ __forceinline__ float4 f4lerp(const float4 a, const float4 b, float t) {
    return make_float4(fmaf(b.x - a.x, t, a.x),
                       fmaf(b.y - a.y, t, a.y),
                       fmaf(b.z - a.z, t, a.z),
                       0.f);
}

__global__ __launch_bounds__(256) void slice_kernel(
    const float* __restrict__ guide, const float4* __restrict__ pre,
    const float* __restrict__ cw, const float* __restrict__ cbias,
    float* __restrict__ out)
{
    constexpr int PT = HWp / 4;  // float4 positions per plane
    int t = blockIdx.x * blockDim.x + threadIdx.x;
    if (t >= N_ * PT) return;
    int n = t / PT;
    int p4 = t - n * PT;

    const float4* gR = (const float4*)(guide + (size_t)(n * 3 + 0) * HWp);
    const float4* gG = (const float4*)(guide + (size_t)(n * 3 + 1) * HWp);
    const float4* gB = (const float4*)(guide + (size_t)(n * 3 + 2) * HWp);
    float4 r4 = gR[p4];
    float4 g4 = gG[p4];
    float4 b4 = gB[p4];

    const float4* __restrict__ P = pre + (size_t)n * CELLS;

    // guide-channel part of the conv + bias (uniform -> scalar loads)
    float w0r = cw[9],  w0g = cw[10], w0b = cw[11];
    float w1r = cw[21], w1g = cw[22], w1b = cw[23];
    float w2r = cw[33], w2g = cw[34], w2b = cw[35];
    float bi0 = cbias[0], bi1 = cbias[1], bi2 = cbias[2];

    float rr[4] = {r4.x, r4.y, r4.z, r4.w};
    float gg[4] = {g4.x, g4.y, g4.z, g4.w};
    float bb[4] = {b4.x, b4.y, b4.z, b4.w};
    float o0[4], o1[4], o2[4];

#pragma unroll
    for (int j = 0; j < 4; ++j) {
        float cr = fminf(fmaxf(rr[j], 0.f), 1.f) * 15.f;
        float cg = fminf(fmaxf(gg[j], 0.f), 1.f) * 15.f;
        float cb = fminf(fmaxf(bb[j], 0.f), 1.f) * 15.f;
        int ir = min((int)cr, 14);   // cr >= 0, trunc == floor
        int ig = min((int)cg, 14);
        int ib = min((int)cb, 14);
        float fr = cr - (float)ir;
        float fg = cg - (float)ig;
        float fb = cb - (float)ib;
        int base = (ir * 16 + ig) * 16 + ib;

        // b and b+1 cells are contiguous (32 B): 4 corner-pair fetches
        float4 c000 = P[base];
        float4 c001 = P[base + 1];
        float4 c010 = P[base + 16];
        float4 c011 = P[base + 17];
        float4 c100 = P[base + 256];
        float4 c101 = P[base + 257];
        float4 c110 = P[base + 272];
        float4 c111 = P[base + 273];

        float4 v00 = f4lerp(c000, c001, fb);
        float4 v01 = f4lerp(c010, c011, fb);
        float4 v10 = f4lerp(c100, c101, fb);
        float4 v11 = f4lerp(c110, c111, fb);
        float4 v0  = f4lerp(v00, v01, fg);
        float4 v1  = f4lerp(v10, v11, fg);
        float4 v   = f4lerp(v0, v1, fr);

        o0[j] = v.x + fmaf(w0r, rr[j], fmaf(w0g, gg[j], fmaf(w0b, bb[j], bi0)));
        o1[j] = v.y + fmaf(w1r, rr[j], fmaf(w1g, gg[j], fmaf(w1b, bb[j], bi1)));
        o2[j] = v.z + fmaf(w2r, rr[j], fmaf(w2g, gg[j], fmaf(w2b, bb[j], bi2)));
    }

    float4* oR = (float4*)(out + (size_t)(n * 3 + 0) * HWp);
    float4* oG = (float4*)(out + (size_t)(n * 3 + 1) * HWp);
    float4* oB = (float4*)(out + (size_t)(n * 3 + 2) * HWp);
    oR[p4] = make_float4(o0[0], o0[1], o0[2], o0[3]);
    oG[p4] = make_float4(o1[0], o1[1], o1[2], o1[3]);
    oB[p4] = make_float4(o2[0], o2[1], o2[2], o2[3]);
}

extern "C" void kernel_launch(void* const* d_in, const int* in_sizes, int n_in,
                              void* d_out, int out_size, void* d_ws, size_t ws_size,
                              hipStream_t stream) {
    const float* grid  = (const float*)d_in[0];
    const float* guide = (const float*)d_in[1];
    const float* cw    = (const float*)d_in[2];
    const float* cb    = (const float*)d_in[3];
    float* out  = (float*)d_out;
    float4* pre = (float4*)d_ws;  // N_*CELLS float4 = 256 KB

    fold_grid_kernel<<<(N_ * CELLS + 255) / 256, 256, 0, stream>>>(grid, cw, pre);

    constexpr int total = N_ * (HWp / 4);
    slice_kernel<<<(total + 255) / 256, 256, 0, stream>>>(guide, pre, cw, cb, out);
}

// Round 2
// 123.166 us; speedup vs baseline: 1.1746x; 1.1746x over previous
//
#include <hip/hip_runtime.h>

static constexpr int N_ = 4;
static constexpr int C_ = 9;
static constexpr int D_ = 16;
static constexpr int HWp = 1024 * 1024;
static constexpr int CELLS = D_ * D_ * D_;  // 4096
static constexpr int PT = HWp / 4;          // 262144 float4 positions per image
static constexpr int TPB = 512;
static constexpr int BPI = 256;             // blocks per image

// Fold the 1x1 conv's grid-channel part into the grid:
// pre[n][cell] = float4( sum_c w[0,c]*g, sum_c w[1,c]*g, sum_c w[2,c]*g, 0 )
__global__ __launch_bounds__(256) void fold_grid_kernel(
    const float* __restrict__ grid, const float* __restrict__ cw,
    float4* __restrict__ pre)
{
    int t = blockIdx.x * blockDim.x + threadIdx.x;
    if (t >= N_ * CELLS) return;
    int n = t >> 12;
    int cell = t & (CELLS - 1);
    const float* g = grid + ((size_t)n * C_) * CELLS + cell;
    float a0 = 0.f, a1 = 0.f, a2 = 0.f;
#pragma unroll
    for (int c = 0; c < C_; ++c) {
        float v = g[(size_t)c * CELLS];
        a0 = fmaf(cw[c], v, a0);
        a1 = fmaf(cw[12 + c], v, a1);
        a2 = fmaf(cw[24 + c], v, a2);
    }
    pre[t] = make_float4(a0, a1, a2, 0.f);
}

__device__ __forceinline__ float4 f4lerp(const float4 a, const float4 b, float t) {
    return make_float4(fmaf(b.x - a.x, t, a.x),
                       fmaf(b.y - a.y, t, a.y),
                       fmaf(b.z - a.z, t, a.z),
                       0.f);
}

__global__ __launch_bounds__(TPB) void slice_kernel(
    const float* __restrict__ guide, const float4* __restrict__ pre,
    const float* __restrict__ cw, const float* __restrict__ cbias,
    float* __restrict__ out)
{
    __shared__ float4 sPre[CELLS];  // 64 KB — one image's folded grid

    const int n  = blockIdx.x >> 8;        // image index (BPI = 256)
    const int bi = blockIdx.x & (BPI - 1); // block index within image

    // Stage this image's 64 KB table into LDS (L2-resident after fold kernel)
    const float4* __restrict__ P = pre + (size_t)n * CELLS;
#pragma unroll
    for (int i = 0; i < CELLS / TPB; ++i)
        sPre[i * TPB + threadIdx.x] = P[i * TPB + threadIdx.x];
    __syncthreads();

    const float4* gR = (const float4*)(guide + (size_t)(n * 3 + 0) * HWp);
    const float4* gG = (const float4*)(guide + (size_t)(n * 3 + 1) * HWp);
    const float4* gB = (const float4*)(guide + (size_t)(n * 3 + 2) * HWp);
    float4* oR = (float4*)(out + (size_t)(n * 3 + 0) * HWp);
    float4* oG = (float4*)(out + (size_t)(n * 3 + 1) * HWp);
    float4* oB = (float4*)(out + (size_t)(n * 3 + 2) * HWp);

    // guide-channel part of the conv + bias (wave-uniform -> scalar loads)
    const float w0r = cw[9],  w0g = cw[10], w0b = cw[11];
    const float w1r = cw[21], w1g = cw[22], w1b = cw[23];
    const float w2r = cw[33], w2g = cw[34], w2b = cw[35];
    const float bi0 = cbias[0], bi1 = cbias[1], bi2 = cbias[2];

    for (int p4 = bi * TPB + threadIdx.x; p4 < PT; p4 += BPI * TPB) {
        float4 r4 = gR[p4];
        float4 g4 = gG[p4];
        float4 b4 = gB[p4];

        float rr[4] = {r4.x, r4.y, r4.z, r4.w};
        float gg[4] = {g4.x, g4.y, g4.z, g4.w};
        float bb[4] = {b4.x, b4.y, b4.z, b4.w};
        float o0[4], o1[4], o2[4];

#pragma unroll
        for (int j = 0; j < 4; ++j) {
            float cr = fminf(fmaxf(rr[j], 0.f), 1.f) * 15.f;
            float cg = fminf(fmaxf(gg[j], 0.f), 1.f) * 15.f;
            float cb = fminf(fmaxf(bb[j], 0.f), 1.f) * 15.f;
            int ir = min((int)cr, 14);   // cr >= 0, trunc == floor
            int ig = min((int)cg, 14);
            int ib = min((int)cb, 14);
            float fr = cr - (float)ir;
            float fg = cg - (float)ig;
            float fb = cb - (float)ib;
            int base = (ir * 16 + ig) * 16 + ib;

            float4 c000 = sPre[base];
            float4 c001 = sPre[base + 1];
            float4 c010 = sPre[base + 16];
            float4 c011 = sPre[base + 17];
            float4 c100 = sPre[base + 256];
            float4 c101 = sPre[base + 257];
            float4 c110 = sPre[base + 272];
            float4 c111 = sPre[base + 273];

            float4 v00 = f4lerp(c000, c001, fb);
            float4 v01 = f4lerp(c010, c011, fb);
            float4 v10 = f4lerp(c100, c101, fb);
            float4 v11 = f4lerp(c110, c111, fb);
            float4 v0  = f4lerp(v00, v01, fg);
            float4 v1  = f4lerp(v10, v11, fg);
            float4 v   = f4lerp(v0, v1, fr);

            o0[j] = v.x + fmaf(w0r, rr[j], fmaf(w0g, gg[j], fmaf(w0b, bb[j], bi0)));
            o1[j] = v.y + fmaf(w1r, rr[j], fmaf(w1g, gg[j], fmaf(w1b, bb[j], bi1)));
            o2[j] = v.z + fmaf(w2r, rr[j], fmaf(w2g, gg[j], fmaf(w2b, bb[j], bi2)));
        }

        oR[p4] = make_float4(o0[0], o0[1], o0[2], o0[3]);
        oG[p4] = make_float4(o1[0], o1[1], o1[2], o1[3]);
        oB[p4] = make_float4(o2[0], o2[1], o2[2], o2[3]);
    }
}

extern "C" void kernel_launch(void* const* d_in, const int* in_sizes, int n_in,
                              void* d_out, int out_size, void* d_ws, size_t ws_size,
                              hipStream_t stream) {
    const float* grid  = (const float*)d_in[0];
    const float* guide = (const float*)d_in[1];
    const float* cw    = (const float*)d_in[2];
    const float* cb    = (const float*)d_in[3];
    float* out  = (float*)d_out;
    float4* pre = (float4*)d_ws;  // N_*CELLS float4 = 256 KB

    fold_grid_kernel<<<(N_ * CELLS + 255) / 256, 256, 0, stream>>>(grid, cw, pre);

    slice_kernel<<<N_ * BPI, TPB, 0, stream>>>(guide, pre, cw, cb, out);
}